// Round 2
// baseline (441.134 us; speedup 1.0000x reference)
//
#include <hip/hip_runtime.h>

#define F 128     // F_IN == H == 128
#define COUT 40
#define TR 64     // row tile for gemm+reduce

// ---------------- zero deg + t + s ----------------
__global__ void k_zero(int* __restrict__ deg, float* __restrict__ t,
                       float* __restrict__ s, int n) {
  int i = blockIdx.x * blockDim.x + threadIdx.x;
  int stride = gridDim.x * blockDim.x;
  for (; i < n; i += stride) { deg[i] = 0; t[i] = 0.f; }
  if (blockIdx.x == 0 && threadIdx.x < F) s[threadIdx.x] = 0.f;
}

// ---------------- degree histogram over row ----------------
__global__ void k_hist(const int* __restrict__ row, int E, int* __restrict__ deg) {
  int e = blockIdx.x * blockDim.x + threadIdx.x;
  if (e < E) atomicAdd(&deg[row[e]], 1);
}

// ---------------- scan stage A: per-256-chunk sums ----------------
__global__ void k_scan_a(const int* __restrict__ deg, int N, int* __restrict__ bsum) {
  __shared__ int sm[256];
  int t = threadIdx.x;
  int i = blockIdx.x * 256 + t;
  sm[t] = (i < N) ? deg[i] : 0;
  __syncthreads();
  for (int off = 128; off > 0; off >>= 1) {
    if (t < off) sm[t] += sm[t + off];
    __syncthreads();
  }
  if (t == 0) bsum[blockIdx.x] = sm[0];
}

// ---------------- scan stage B: exclusive scan of block sums (<=512) ----------------
__global__ void k_scan_b(const int* __restrict__ bsum, int nb, int* __restrict__ bpre) {
  __shared__ int sm[512];
  int t = threadIdx.x;  // 512 threads
  int v = (t < nb) ? bsum[t] : 0;
  sm[t] = v;
  __syncthreads();
  for (int off = 1; off < 512; off <<= 1) {
    int x = sm[t];
    int y = (t >= off) ? sm[t - off] : 0;
    __syncthreads();
    sm[t] = x + y;
    __syncthreads();
  }
  if (t < nb) bpre[t] = sm[t] - v;  // exclusive
}

// ---------------- scan stage C: row_ptr, dis; deg -> fill=0 ----------------
__global__ void k_scan_c(int* __restrict__ deg, int N, int E,
                         const int* __restrict__ bpre,
                         int* __restrict__ row_ptr,
                         float* __restrict__ dis) {
  __shared__ int sm[256];
  int t = threadIdx.x;
  int i = blockIdx.x * 256 + t;
  int d = (i < N) ? deg[i] : 0;
  sm[t] = d;
  __syncthreads();
  for (int off = 1; off < 256; off <<= 1) {
    int x = sm[t];
    int y = (t >= off) ? sm[t - off] : 0;
    __syncthreads();
    sm[t] = x + y;
    __syncthreads();
  }
  if (i < N) {
    row_ptr[i] = bpre[blockIdx.x] + sm[t] - d;  // exclusive prefix
    dis[i] = rsqrtf(1.0f + (float)d);
    deg[i] = 0;          // reuse as fill counter
  }
  if (i == 0) row_ptr[N] = E;
}

// ---------------- CSR fill (col only) + t[c] += dis[r] ----------------
__global__ void k_fill(const int* __restrict__ row, const int* __restrict__ col, int E,
                       const float* __restrict__ dis,
                       const int* __restrict__ row_ptr,
                       int* __restrict__ fill,
                       int* __restrict__ csr,
                       float* __restrict__ tcol) {
  int e = blockIdx.x * blockDim.x + threadIdx.x;
  if (e >= E) return;
  int r = row[e], c = col[e];
  int slot = row_ptr[r] + atomicAdd(&fill[r], 1);
  csr[slot] = c;
  atomicAdd(&tcol[c], dis[r]);
}

// ---------------- spmm: one wave per row, z1 = Ahat * X ----------------
__global__ void __launch_bounds__(256) k_spmm(
    const float* __restrict__ X,
    const int* __restrict__ row_ptr,
    const float* __restrict__ dis,
    const int* __restrict__ csr,
    float* __restrict__ z1, int N) {
  int wave = (blockIdx.x * blockDim.x + threadIdx.x) >> 6;
  int lane = threadIdx.x & 63;
  if (wave >= N) return;
  int rowi = wave;
  float dr = dis[rowi];
  const float2* xr = (const float2*)(X + (long)rowi * F);
  float2 self = xr[lane];
  float2 acc = make_float2(0.f, 0.f);
  int e0 = row_ptr[rowi], e1 = row_ptr[rowi + 1];
  int e = e0;
  for (; e + 4 <= e1; e += 4) {
    int c0 = csr[e], c1 = csr[e + 1], c2 = csr[e + 2], c3 = csr[e + 3];
    float w0 = dis[c0], w1 = dis[c1], w2 = dis[c2], w3 = dis[c3];
    float2 x0 = ((const float2*)(X + (long)c0 * F))[lane];
    float2 x1 = ((const float2*)(X + (long)c1 * F))[lane];
    float2 x2 = ((const float2*)(X + (long)c2 * F))[lane];
    float2 x3 = ((const float2*)(X + (long)c3 * F))[lane];
    acc.x += w0 * x0.x + w1 * x1.x + w2 * x2.x + w3 * x3.x;
    acc.y += w0 * x0.y + w1 * x1.y + w2 * x2.y + w3 * x3.y;
  }
  for (; e < e1; ++e) {
    int c = csr[e];
    float w = dis[c];
    float2 xv = ((const float2*)(X + (long)c * F))[lane];
    acc.x += w * xv.x;
    acc.y += w * xv.y;
  }
  // z1 = dr * (sum_e dis[c]*x[c]) + dr^2 * x[self]
  acc.x = dr * (acc.x + dr * self.x);
  acc.y = dr * (acc.y + dr * self.y);
  ((float2*)(z1 + (long)rowi * F))[lane] = acc;
}

// ---------------- fused GEMM (z1@W1+b1), relu, weighted column reduction ----------------
__global__ void __launch_bounds__(256) k_gemm_red(
    const float* __restrict__ z1,
    const float* __restrict__ W1,
    const float* __restrict__ b1,
    const float* __restrict__ dis,
    const float* __restrict__ tcol,
    float* __restrict__ s, int N) {
  __shared__ float zt[TR][F];      // 32 KB
  __shared__ float wsl[16][F];     // 8 KB
  __shared__ float sred[16][F];    // 8 KB
  int t = threadIdx.x;
  int g0 = blockIdx.x * TR;

  // stage z1 tile (zeros past N)
  for (int it = 0; it < 8; ++it) {
    int idx = (it * 256 + t) * 4;
    int r = idx >> 7;
    int c = idx & 127;
    int g = g0 + r;
    float4 v = make_float4(0.f, 0.f, 0.f, 0.f);
    if (g < N) v = *(const float4*)(z1 + (long)g * F + c);
    *(float4*)(&zt[r][c]) = v;
  }

  int tr = t >> 4, tc = t & 15;    // 16x16 thread grid: 4 rows x 8 cols each
  float acc[4][8] = {};

  for (int kb = 0; kb < F; kb += 16) {
    __syncthreads();
    for (int it = 0; it < 2; ++it) {
      int idx = (it * 256 + t) * 4;
      int kk = idx >> 7;
      int c = idx & 127;
      *(float4*)(&wsl[kk][c]) = *(const float4*)(W1 + (long)(kb + kk) * F + c);
    }
    __syncthreads();
#pragma unroll
    for (int kk = 0; kk < 16; ++kk) {
      float a0 = zt[4 * tr + 0][kb + kk];
      float a1 = zt[4 * tr + 1][kb + kk];
      float a2 = zt[4 * tr + 2][kb + kk];
      float a3 = zt[4 * tr + 3][kb + kk];
      float b[8];
      *(float4*)&b[0] = *(float4*)(&wsl[kk][8 * tc]);
      *(float4*)&b[4] = *(float4*)(&wsl[kk][8 * tc + 4]);
#pragma unroll
      for (int j = 0; j < 8; ++j) {
        acc[0][j] += a0 * b[j];
        acc[1][j] += a1 * b[j];
        acc[2][j] += a2 * b[j];
        acc[3][j] += a3 * b[j];
      }
    }
  }

  // epilogue: relu + c-weighted row reduction; cw = dis*(dis + t)
  float sacc[8] = {};
#pragma unroll
  for (int j = 0; j < 4; ++j) {
    int g = g0 + 4 * tr + j;
    float cw = 0.f;
    if (g < N) {
      float d = dis[g];
      cw = d * (d + tcol[g]);
    }
#pragma unroll
    for (int q = 0; q < 8; ++q) {
      float h = acc[j][q] + b1[8 * tc + q];
      h = h > 0.f ? h : 0.f;
      sacc[q] += cw * h;
    }
  }
#pragma unroll
  for (int q = 0; q < 8; ++q) sred[tr][8 * tc + q] = sacc[q];
  __syncthreads();
  if (t < F) {
    float v = 0.f;
#pragma unroll
    for (int i = 0; i < 16; ++i) v += sred[i][t];
    atomicAdd(&s[t], v);
  }
}

// ---------------- finalize: out = (s/N)@W2 + b2 ----------------
__global__ void k_out(const float* __restrict__ s, const float* __restrict__ W2,
                      const float* __restrict__ b2, float* __restrict__ out,
                      float invN) {
  int j = threadIdx.x;
  if (j >= COUT) return;
  float acc = b2[j];
  for (int k = 0; k < F; ++k) acc += (s[k] * invN) * W2[k * COUT + j];
  out[j] = acc;
}

extern "C" void kernel_launch(void* const* d_in, const int* in_sizes, int n_in,
                              void* d_out, int out_size, void* d_ws, size_t ws_size,
                              hipStream_t stream) {
  const int* edge = (const int*)d_in[0];
  const float* X  = (const float*)d_in[1];
  const float* W1 = (const float*)d_in[2];
  const float* b1 = (const float*)d_in[3];
  const float* W2 = (const float*)d_in[4];
  const float* b2 = (const float*)d_in[5];
  float* out = (float*)d_out;

  int E = in_sizes[0] / 2;
  int N = in_sizes[1] / F;
  const int* row = edge;
  const int* col = edge + E;

  char* w = (char*)d_ws;
  auto alloc = [&](size_t bytes) {
    char* p = w;
    w += (bytes + 255) & ~(size_t)255;
    return p;
  };
  int*   deg     = (int*)alloc((size_t)N * 4);          // later: fill counters
  int*   row_ptr = (int*)alloc(((size_t)N + 1) * 4);
  float* dis     = (float*)alloc((size_t)N * 4);
  float* tcol    = (float*)alloc((size_t)N * 4);
  float* s       = (float*)alloc(512);
  int*   bsum    = (int*)alloc(512 * 4);
  int*   bpre    = (int*)alloc(512 * 4);
  int*   csr     = (int*)alloc((size_t)E * 4);
  float* z1      = (float*)alloc((size_t)N * F * 4);

  int nb = (N + 255) / 256;

  k_zero  <<<nb, 256, 0, stream>>>(deg, tcol, s, N);
  k_hist  <<<(E + 255) / 256, 256, 0, stream>>>(row, E, deg);
  k_scan_a<<<nb, 256, 0, stream>>>(deg, N, bsum);
  k_scan_b<<<1, 512, 0, stream>>>(bsum, nb, bpre);
  k_scan_c<<<nb, 256, 0, stream>>>(deg, N, E, bpre, row_ptr, dis);
  k_fill  <<<(E + 255) / 256, 256, 0, stream>>>(row, col, E, dis, row_ptr, deg, csr, tcol);
  k_spmm  <<<(N + 3) / 4, 256, 0, stream>>>(X, row_ptr, dis, csr, z1, N);
  k_gemm_red<<<(N + TR - 1) / TR, 256, 0, stream>>>(z1, W1, b1, dis, tcol, s, N);
  k_out   <<<1, 64, 0, stream>>>(s, W2, b2, out, 1.0f / (float)N);
}

// Round 3
// 343.008 us; speedup vs baseline: 1.2861x; 1.2861x over previous
//
#include <hip/hip_runtime.h>

#define F 128      // F_IN == H == 128
#define COUT 40
#define TR 64      // row tile for gemm+reduce
#define BSH 8      // 256 rows per bucket
#define CAP 6144   // staging slots per bucket (mean 4096, sigma 64 -> +32 sigma)
#define CH 8192    // edges per block in k_bucket

// ---------------- zero tcol + s + bcount ----------------
__global__ void k_zero(float* __restrict__ tcol, float* __restrict__ s,
                       int* __restrict__ bcount, int N, int nbuck) {
  int i = blockIdx.x * blockDim.x + threadIdx.x;
  if (i < N) tcol[i] = 0.f;
  if (i < nbuck) bcount[i] = 0;
  if (i < F) s[i] = 0.f;
}

// ---------------- phase A: bucket edges by row>>8 ----------------
__global__ void __launch_bounds__(256) k_bucket(
    const int* __restrict__ row, const int* __restrict__ col, int E,
    int* __restrict__ bcount, unsigned* __restrict__ staging, int nbuck) {
  __shared__ int hist[512];
  __shared__ int cursor[512];
  int t = threadIdx.x;
  int base = blockIdx.x * CH;
  for (int i = t; i < nbuck; i += 256) hist[i] = 0;
  __syncthreads();
  int n = E - base; if (n > CH) n = CH;
  for (int i = t; i < n; i += 256) {
    int r = row[base + i];
    atomicAdd(&hist[r >> BSH], 1);
  }
  __syncthreads();
  for (int i = t; i < nbuck; i += 256) {
    int c = hist[i];
    cursor[i] = (c > 0) ? (i * CAP + atomicAdd(&bcount[i], c)) : 0;
  }
  __syncthreads();
  for (int i = t; i < n; i += 256) {
    int r = row[base + i];
    int c = col[base + i];
    int b = r >> BSH;
    int dst = atomicAdd(&cursor[b], 1);
    if (dst < (b + 1) * CAP)   // paranoia guard against (impossible) overflow
      staging[dst] = ((unsigned)(r & 255) << 17) | (unsigned)c;
  }
}

// ---------------- tiny scan over bucket counts ----------------
__global__ void k_bscan(int* __restrict__ bcount, int nbuck,
                        int* __restrict__ bbase, int* __restrict__ row_ptr,
                        int N, int E) {
  __shared__ int sm[512];
  int t = threadIdx.x;  // 512 threads
  int v = 0;
  if (t < nbuck) { v = bcount[t]; if (v > CAP) v = CAP; }
  sm[t] = v;
  __syncthreads();
  for (int off = 1; off < 512; off <<= 1) {
    int x = sm[t];
    int y = (t >= off) ? sm[t - off] : 0;
    __syncthreads();
    sm[t] = x + y;
    __syncthreads();
  }
  if (t < nbuck) bbase[t] = sm[t] - v;   // exclusive
  if (t == 0) row_ptr[N] = E;
}

// ---------------- phase B: per-bucket CSR build + row_ptr/dis + tcol ----------------
__global__ void __launch_bounds__(256) k_build(
    const unsigned* __restrict__ staging,
    const int* __restrict__ bcount, const int* __restrict__ bbase,
    int* __restrict__ row_ptr, float* __restrict__ dis,
    float* __restrict__ tcol, int* __restrict__ csr, int N) {
  __shared__ int cnt[256];
  __shared__ int cur[256];
  __shared__ float disl[256];
  int b = blockIdx.x;
  int t = threadIdx.x;
  int r0 = b << BSH;
  int nrows = N - r0; if (nrows > 256) nrows = 256;
  int ecnt = bcount[b]; if (ecnt > CAP) ecnt = CAP;
  const unsigned* sg = staging + (size_t)b * CAP;
  int gb = bbase[b];

  cnt[t] = 0;
  __syncthreads();
  for (int i = t; i < ecnt; i += 256) atomicAdd(&cnt[sg[i] >> 17], 1);
  __syncthreads();
  int d = cnt[t];
  // exclusive scan of cnt (in place, inclusive then subtract)
  for (int off = 1; off < 256; off <<= 1) {
    int x = cnt[t];
    int y = (t >= off) ? cnt[t - off] : 0;
    __syncthreads();
    cnt[t] = x + y;
    __syncthreads();
  }
  int excl = cnt[t] - d;
  if (t < nrows) {
    row_ptr[r0 + t] = gb + excl;
    float r = rsqrtf(1.0f + (float)d);
    dis[r0 + t] = r;
    disl[t] = r;
  }
  cur[t] = gb + excl;
  __syncthreads();
  for (int i = t; i < ecnt; i += 256) {
    unsigned p = sg[i];
    int lr = p >> 17;
    int c = (int)(p & 0x1FFFFu);
    int slot = atomicAdd(&cur[lr], 1);
    csr[slot] = c;
    atomicAdd(&tcol[c], disl[lr]);
  }
}

// ---------------- spmm: one wave per row, z1 = Ahat * X ----------------
__global__ void __launch_bounds__(256) k_spmm(
    const float* __restrict__ X,
    const int* __restrict__ row_ptr,
    const float* __restrict__ dis,
    const int* __restrict__ csr,
    float* __restrict__ z1, int N) {
  int wave = (blockIdx.x * blockDim.x + threadIdx.x) >> 6;
  int lane = threadIdx.x & 63;
  if (wave >= N) return;
  int rowi = wave;
  float dr = dis[rowi];
  const float2* xr = (const float2*)(X + (long)rowi * F);
  float2 self = xr[lane];
  float2 acc = make_float2(0.f, 0.f);
  int e0 = row_ptr[rowi], e1 = row_ptr[rowi + 1];
  int e = e0;
  for (; e + 4 <= e1; e += 4) {
    int c0 = csr[e], c1 = csr[e + 1], c2 = csr[e + 2], c3 = csr[e + 3];
    float w0 = dis[c0], w1 = dis[c1], w2 = dis[c2], w3 = dis[c3];
    float2 x0 = ((const float2*)(X + (long)c0 * F))[lane];
    float2 x1 = ((const float2*)(X + (long)c1 * F))[lane];
    float2 x2 = ((const float2*)(X + (long)c2 * F))[lane];
    float2 x3 = ((const float2*)(X + (long)c3 * F))[lane];
    acc.x += w0 * x0.x + w1 * x1.x + w2 * x2.x + w3 * x3.x;
    acc.y += w0 * x0.y + w1 * x1.y + w2 * x2.y + w3 * x3.y;
  }
  for (; e < e1; ++e) {
    int c = csr[e];
    float w = dis[c];
    float2 xv = ((const float2*)(X + (long)c * F))[lane];
    acc.x += w * xv.x;
    acc.y += w * xv.y;
  }
  acc.x = dr * (acc.x + dr * self.x);
  acc.y = dr * (acc.y + dr * self.y);
  ((float2*)(z1 + (long)rowi * F))[lane] = acc;
}

// ---------------- fused GEMM (z1@W1+b1), relu, weighted column reduction ----------------
__global__ void __launch_bounds__(256) k_gemm_red(
    const float* __restrict__ z1,
    const float* __restrict__ W1,
    const float* __restrict__ b1,
    const float* __restrict__ dis,
    const float* __restrict__ tcol,
    float* __restrict__ s, int N) {
  __shared__ float zt[TR][F];      // 32 KB
  __shared__ float wsl[16][F];     // 8 KB
  __shared__ float sred[16][F];    // 8 KB
  int t = threadIdx.x;
  int g0 = blockIdx.x * TR;

  for (int it = 0; it < 8; ++it) {
    int idx = (it * 256 + t) * 4;
    int r = idx >> 7;
    int c = idx & 127;
    int g = g0 + r;
    float4 v = make_float4(0.f, 0.f, 0.f, 0.f);
    if (g < N) v = *(const float4*)(z1 + (long)g * F + c);
    *(float4*)(&zt[r][c]) = v;
  }

  int tr = t >> 4, tc = t & 15;
  float acc[4][8] = {};

  for (int kb = 0; kb < F; kb += 16) {
    __syncthreads();
    for (int it = 0; it < 2; ++it) {
      int idx = (it * 256 + t) * 4;
      int kk = idx >> 7;
      int c = idx & 127;
      *(float4*)(&wsl[kk][c]) = *(const float4*)(W1 + (long)(kb + kk) * F + c);
    }
    __syncthreads();
#pragma unroll
    for (int kk = 0; kk < 16; ++kk) {
      float a0 = zt[4 * tr + 0][kb + kk];
      float a1 = zt[4 * tr + 1][kb + kk];
      float a2 = zt[4 * tr + 2][kb + kk];
      float a3 = zt[4 * tr + 3][kb + kk];
      float bv[8];
      *(float4*)&bv[0] = *(float4*)(&wsl[kk][8 * tc]);
      *(float4*)&bv[4] = *(float4*)(&wsl[kk][8 * tc + 4]);
#pragma unroll
      for (int j = 0; j < 8; ++j) {
        acc[0][j] += a0 * bv[j];
        acc[1][j] += a1 * bv[j];
        acc[2][j] += a2 * bv[j];
        acc[3][j] += a3 * bv[j];
      }
    }
  }

  float sacc[8] = {};
#pragma unroll
  for (int j = 0; j < 4; ++j) {
    int g = g0 + 4 * tr + j;
    float cw = 0.f;
    if (g < N) {
      float dv = dis[g];
      cw = dv * (dv + tcol[g]);
    }
#pragma unroll
    for (int q = 0; q < 8; ++q) {
      float h = acc[j][q] + b1[8 * tc + q];
      h = h > 0.f ? h : 0.f;
      sacc[q] += cw * h;
    }
  }
#pragma unroll
  for (int q = 0; q < 8; ++q) sred[tr][8 * tc + q] = sacc[q];
  __syncthreads();
  if (t < F) {
    float v = 0.f;
#pragma unroll
    for (int i = 0; i < 16; ++i) v += sred[i][t];
    atomicAdd(&s[t], v);
  }
}

// ---------------- finalize: out = (s/N)@W2 + b2 ----------------
__global__ void k_out(const float* __restrict__ s, const float* __restrict__ W2,
                      const float* __restrict__ b2, float* __restrict__ out,
                      float invN) {
  int j = threadIdx.x;
  if (j >= COUT) return;
  float acc = b2[j];
  for (int k = 0; k < F; ++k) acc += (s[k] * invN) * W2[k * COUT + j];
  out[j] = acc;
}

extern "C" void kernel_launch(void* const* d_in, const int* in_sizes, int n_in,
                              void* d_out, int out_size, void* d_ws, size_t ws_size,
                              hipStream_t stream) {
  const int* edge = (const int*)d_in[0];
  const float* X  = (const float*)d_in[1];
  const float* W1 = (const float*)d_in[2];
  const float* b1 = (const float*)d_in[3];
  const float* W2 = (const float*)d_in[4];
  const float* b2 = (const float*)d_in[5];
  float* out = (float*)d_out;

  int E = in_sizes[0] / 2;
  int N = in_sizes[1] / F;
  const int* row = edge;
  const int* col = edge + E;
  int nbuck = (N + 255) >> BSH;

  char* w = (char*)d_ws;
  auto alloc = [&](size_t bytes) {
    char* p = w;
    w += (bytes + 255) & ~(size_t)255;
    return p;
  };
  float*    tcol    = (float*)alloc((size_t)N * 4);
  float*    dis     = (float*)alloc((size_t)N * 4);
  int*      row_ptr = (int*)alloc(((size_t)N + 1) * 4);
  float*    s       = (float*)alloc(512);
  int*      bcount  = (int*)alloc(512 * 4);
  int*      bbase   = (int*)alloc(512 * 4);
  unsigned* staging = (unsigned*)alloc((size_t)nbuck * CAP * 4);
  int*      csr     = (int*)alloc((size_t)E * 4);
  float*    z1      = (float*)alloc((size_t)N * F * 4);

  k_zero  <<<(N + 255) / 256, 256, 0, stream>>>(tcol, s, bcount, N, nbuck);
  k_bucket<<<(E + CH - 1) / CH, 256, 0, stream>>>(row, col, E, bcount, staging, nbuck);
  k_bscan <<<1, 512, 0, stream>>>(bcount, nbuck, bbase, row_ptr, N, E);
  k_build <<<nbuck, 256, 0, stream>>>(staging, bcount, bbase, row_ptr, dis, tcol, csr, N);
  k_spmm  <<<(N + 3) / 4, 256, 0, stream>>>(X, row_ptr, dis, csr, z1, N);
  k_gemm_red<<<(N + TR - 1) / TR, 256, 0, stream>>>(z1, W1, b1, dis, tcol, s, N);
  k_out   <<<1, 64, 0, stream>>>(s, W2, b2, out, 1.0f / (float)N);
}

// Round 4
// 300.153 us; speedup vs baseline: 1.4697x; 1.1428x over previous
//
#include <hip/hip_runtime.h>

#define F 128      // F_IN == H == 128
#define COUT 40
#define TR 64      // row tile for gemm+reduce
#define BSH 8      // 256 rows per bucket
#define CAP 6144   // staging slots per bucket (mean 4096, sigma 64 -> +32 sigma)
#define CH 8192    // edges per block in k_bucket

typedef unsigned int  u32;
typedef unsigned short u16;

__device__ inline u32 bf16_rne(float f) {
  u32 u = __float_as_uint(f);
  u += 0x7FFFu + ((u >> 16) & 1u);   // round-to-nearest-even (no NaN inputs)
  return u >> 16;
}

// ---------------- zero tcol + s + bcount ----------------
__global__ void k_zero(float* __restrict__ tcol, float* __restrict__ s,
                       int* __restrict__ bcount, int N, int nbuck) {
  int i = blockIdx.x * blockDim.x + threadIdx.x;
  if (i < N) tcol[i] = 0.f;
  if (i < nbuck) bcount[i] = 0;
  if (i < F) s[i] = 0.f;
}

// ---------------- cast X (f32) -> Xh (bf16), 8 elems/thread ----------------
__global__ void __launch_bounds__(256) k_cast(const float4* __restrict__ X,
                                              uint4* __restrict__ Xh, int nvec) {
  int i = blockIdx.x * blockDim.x + threadIdx.x;
  if (i >= nvec) return;
  float4 a = X[2 * i], b = X[2 * i + 1];
  uint4 o;
  o.x = bf16_rne(a.x) | (bf16_rne(a.y) << 16);
  o.y = bf16_rne(a.z) | (bf16_rne(a.w) << 16);
  o.z = bf16_rne(b.x) | (bf16_rne(b.y) << 16);
  o.w = bf16_rne(b.z) | (bf16_rne(b.w) << 16);
  Xh[i] = o;
}

// ---------------- phase A: bucket edges by row>>8 ----------------
__global__ void __launch_bounds__(256) k_bucket(
    const int* __restrict__ row, const int* __restrict__ col, int E,
    int* __restrict__ bcount, unsigned* __restrict__ staging, int nbuck) {
  __shared__ int hist[512];
  __shared__ int cursor[512];
  int t = threadIdx.x;
  int base = blockIdx.x * CH;
  for (int i = t; i < nbuck; i += 256) hist[i] = 0;
  __syncthreads();
  int n = E - base; if (n > CH) n = CH;
  for (int i = t; i < n; i += 256) {
    int r = row[base + i];
    atomicAdd(&hist[r >> BSH], 1);
  }
  __syncthreads();
  for (int i = t; i < nbuck; i += 256) {
    int c = hist[i];
    cursor[i] = (c > 0) ? (i * CAP + atomicAdd(&bcount[i], c)) : 0;
  }
  __syncthreads();
  for (int i = t; i < n; i += 256) {
    int r = row[base + i];
    int c = col[base + i];
    int b = r >> BSH;
    int dst = atomicAdd(&cursor[b], 1);
    if (dst < (b + 1) * CAP)
      staging[dst] = ((unsigned)(r & 255) << 17) | (unsigned)c;
  }
}

// ---------------- tiny scan over bucket counts ----------------
__global__ void k_bscan(int* __restrict__ bcount, int nbuck,
                        int* __restrict__ bbase, int* __restrict__ row_ptr,
                        int N, int E) {
  __shared__ int sm[512];
  int t = threadIdx.x;  // 512 threads
  int v = 0;
  if (t < nbuck) { v = bcount[t]; if (v > CAP) v = CAP; }
  sm[t] = v;
  __syncthreads();
  for (int off = 1; off < 512; off <<= 1) {
    int x = sm[t];
    int y = (t >= off) ? sm[t - off] : 0;
    __syncthreads();
    sm[t] = x + y;
    __syncthreads();
  }
  if (t < nbuck) bbase[t] = sm[t] - v;   // exclusive
  if (t == 0) row_ptr[N] = E;
}

// ---------------- phase B: per-bucket CSR build + row_ptr/dis + tcol ----------------
__global__ void __launch_bounds__(256) k_build(
    const unsigned* __restrict__ staging,
    const int* __restrict__ bcount, const int* __restrict__ bbase,
    int* __restrict__ row_ptr, float* __restrict__ dis,
    float* __restrict__ tcol, int* __restrict__ csr, int N) {
  __shared__ int cnt[256];
  __shared__ int cur[256];
  __shared__ float disl[256];
  int b = blockIdx.x;
  int t = threadIdx.x;
  int r0 = b << BSH;
  int nrows = N - r0; if (nrows > 256) nrows = 256;
  int ecnt = bcount[b]; if (ecnt > CAP) ecnt = CAP;
  const unsigned* sg = staging + (size_t)b * CAP;
  int gb = bbase[b];

  cnt[t] = 0;
  __syncthreads();
  for (int i = t; i < ecnt; i += 256) atomicAdd(&cnt[sg[i] >> 17], 1);
  __syncthreads();
  int d = cnt[t];
  for (int off = 1; off < 256; off <<= 1) {
    int x = cnt[t];
    int y = (t >= off) ? cnt[t - off] : 0;
    __syncthreads();
    cnt[t] = x + y;
    __syncthreads();
  }
  int excl = cnt[t] - d;
  if (t < nrows) {
    row_ptr[r0 + t] = gb + excl;
    float r = rsqrtf(1.0f + (float)d);
    dis[r0 + t] = r;
    disl[t] = r;
  }
  cur[t] = gb + excl;
  __syncthreads();
  for (int i = t; i < ecnt; i += 256) {
    unsigned p = sg[i];
    int lr = p >> 17;
    int c = (int)(p & 0x1FFFFu);
    int slot = atomicAdd(&cur[lr], 1);
    csr[slot] = c;
    atomicAdd(&tcol[c], disl[lr]);
  }
}

// ---------------- spmm: one wave per row, z1 = Ahat * X (bf16 gather) ----------------
__global__ void __launch_bounds__(256) k_spmm(
    const u16* __restrict__ Xh,
    const int* __restrict__ row_ptr,
    const float* __restrict__ dis,
    const int* __restrict__ csr,
    float* __restrict__ z1, int N) {
  int wave = (blockIdx.x * blockDim.x + threadIdx.x) >> 6;
  int lane = threadIdx.x & 63;
  if (wave >= N) return;
  float dr = dis[wave];
  u32 sv = ((const u32*)(Xh + (size_t)wave * F))[lane];
  float2 acc = make_float2(0.f, 0.f);
  int e0 = row_ptr[wave], e1 = row_ptr[wave + 1];
  int e = e0;
  for (; e + 8 <= e1; e += 8) {
    int c[8]; u32 v[8]; float w[8];
#pragma unroll
    for (int j = 0; j < 8; ++j) c[j] = csr[e + j];
#pragma unroll
    for (int j = 0; j < 8; ++j) v[j] = ((const u32*)(Xh + (size_t)c[j] * F))[lane];
#pragma unroll
    for (int j = 0; j < 8; ++j) w[j] = dis[c[j]];
#pragma unroll
    for (int j = 0; j < 8; ++j) {
      acc.x += w[j] * __uint_as_float(v[j] << 16);
      acc.y += w[j] * __uint_as_float(v[j] & 0xFFFF0000u);
    }
  }
  for (; e + 4 <= e1; e += 4) {
    int c[4]; u32 v[4]; float w[4];
#pragma unroll
    for (int j = 0; j < 4; ++j) c[j] = csr[e + j];
#pragma unroll
    for (int j = 0; j < 4; ++j) v[j] = ((const u32*)(Xh + (size_t)c[j] * F))[lane];
#pragma unroll
    for (int j = 0; j < 4; ++j) w[j] = dis[c[j]];
#pragma unroll
    for (int j = 0; j < 4; ++j) {
      acc.x += w[j] * __uint_as_float(v[j] << 16);
      acc.y += w[j] * __uint_as_float(v[j] & 0xFFFF0000u);
    }
  }
  for (; e < e1; ++e) {
    int c = csr[e];
    float w = dis[c];
    u32 v = ((const u32*)(Xh + (size_t)c * F))[lane];
    acc.x += w * __uint_as_float(v << 16);
    acc.y += w * __uint_as_float(v & 0xFFFF0000u);
  }
  // z1 = dr * (sum + dr * self)
  acc.x = dr * (acc.x + dr * __uint_as_float(sv << 16));
  acc.y = dr * (acc.y + dr * __uint_as_float(sv & 0xFFFF0000u));
  ((float2*)(z1 + (size_t)wave * F))[lane] = acc;
}

// ---------------- fused GEMM (z1@W1+b1), relu, weighted column reduction ----------------
__global__ void __launch_bounds__(256) k_gemm_red(
    const float* __restrict__ z1,
    const float* __restrict__ W1,
    const float* __restrict__ b1,
    const float* __restrict__ dis,
    const float* __restrict__ tcol,
    float* __restrict__ s, int N) {
  __shared__ float zt[TR][F];      // 32 KB
  __shared__ float wsl[16][F];     // 8 KB
  __shared__ float sred[16][F];    // 8 KB
  int t = threadIdx.x;
  int g0 = blockIdx.x * TR;

  for (int it = 0; it < 8; ++it) {
    int idx = (it * 256 + t) * 4;
    int r = idx >> 7;
    int c = idx & 127;
    int g = g0 + r;
    float4 v = make_float4(0.f, 0.f, 0.f, 0.f);
    if (g < N) v = *(const float4*)(z1 + (long)g * F + c);
    *(float4*)(&zt[r][c]) = v;
  }

  int tr = t >> 4, tc = t & 15;
  float acc[4][8] = {};

  for (int kb = 0; kb < F; kb += 16) {
    __syncthreads();
    for (int it = 0; it < 2; ++it) {
      int idx = (it * 256 + t) * 4;
      int kk = idx >> 7;
      int c = idx & 127;
      *(float4*)(&wsl[kk][c]) = *(const float4*)(W1 + (long)(kb + kk) * F + c);
    }
    __syncthreads();
#pragma unroll
    for (int kk = 0; kk < 16; ++kk) {
      float a0 = zt[4 * tr + 0][kb + kk];
      float a1 = zt[4 * tr + 1][kb + kk];
      float a2 = zt[4 * tr + 2][kb + kk];
      float a3 = zt[4 * tr + 3][kb + kk];
      float bv[8];
      *(float4*)&bv[0] = *(float4*)(&wsl[kk][8 * tc]);
      *(float4*)&bv[4] = *(float4*)(&wsl[kk][8 * tc + 4]);
#pragma unroll
      for (int j = 0; j < 8; ++j) {
        acc[0][j] += a0 * bv[j];
        acc[1][j] += a1 * bv[j];
        acc[2][j] += a2 * bv[j];
        acc[3][j] += a3 * bv[j];
      }
    }
  }

  float sacc[8] = {};
#pragma unroll
  for (int j = 0; j < 4; ++j) {
    int g = g0 + 4 * tr + j;
    float cw = 0.f;
    if (g < N) {
      float dv = dis[g];
      cw = dv * (dv + tcol[g]);
    }
#pragma unroll
    for (int q = 0; q < 8; ++q) {
      float h = acc[j][q] + b1[8 * tc + q];
      h = h > 0.f ? h : 0.f;
      sacc[q] += cw * h;
    }
  }
#pragma unroll
  for (int q = 0; q < 8; ++q) sred[tr][8 * tc + q] = sacc[q];
  __syncthreads();
  if (t < F) {
    float v = 0.f;
#pragma unroll
    for (int i = 0; i < 16; ++i) v += sred[i][t];
    atomicAdd(&s[t], v);
  }
}

// ---------------- finalize: out = (s/N)@W2 + b2 ----------------
__global__ void k_out(const float* __restrict__ s, const float* __restrict__ W2,
                      const float* __restrict__ b2, float* __restrict__ out,
                      float invN) {
  int j = threadIdx.x;
  if (j >= COUT) return;
  float acc = b2[j];
  for (int k = 0; k < F; ++k) acc += (s[k] * invN) * W2[k * COUT + j];
  out[j] = acc;
}

extern "C" void kernel_launch(void* const* d_in, const int* in_sizes, int n_in,
                              void* d_out, int out_size, void* d_ws, size_t ws_size,
                              hipStream_t stream) {
  const int* edge = (const int*)d_in[0];
  const float* X  = (const float*)d_in[1];
  const float* W1 = (const float*)d_in[2];
  const float* b1 = (const float*)d_in[3];
  const float* W2 = (const float*)d_in[4];
  const float* b2 = (const float*)d_in[5];
  float* out = (float*)d_out;

  int E = in_sizes[0] / 2;
  int N = in_sizes[1] / F;
  const int* row = edge;
  const int* col = edge + E;
  int nbuck = (N + 255) >> BSH;

  char* w = (char*)d_ws;
  auto alloc = [&](size_t bytes) {
    char* p = w;
    w += (bytes + 255) & ~(size_t)255;
    return p;
  };
  float*    tcol    = (float*)alloc((size_t)N * 4);
  float*    dis     = (float*)alloc((size_t)N * 4);
  int*      row_ptr = (int*)alloc(((size_t)N + 1) * 4);
  float*    s       = (float*)alloc(512);
  int*      bcount  = (int*)alloc(512 * 4);
  int*      bbase   = (int*)alloc(512 * 4);
  u16*      Xh      = (u16*)alloc((size_t)N * F * 2);
  unsigned* staging = (unsigned*)alloc((size_t)nbuck * CAP * 4);
  int*      csr     = (int*)alloc((size_t)E * 4);
  float*    z1      = (float*)alloc((size_t)N * F * 4);

  int nvec = (N * F) / 8;   // N*F divisible by 8

  k_zero  <<<(N + 255) / 256, 256, 0, stream>>>(tcol, s, bcount, N, nbuck);
  k_cast  <<<(nvec + 255) / 256, 256, 0, stream>>>((const float4*)X, (uint4*)Xh, nvec);
  k_bucket<<<(E + CH - 1) / CH, 256, 0, stream>>>(row, col, E, bcount, staging, nbuck);
  k_bscan <<<1, 512, 0, stream>>>(bcount, nbuck, bbase, row_ptr, N, E);
  k_build <<<nbuck, 256, 0, stream>>>(staging, bcount, bbase, row_ptr, dis, tcol, csr, N);
  k_spmm  <<<(N + 3) / 4, 256, 0, stream>>>(Xh, row_ptr, dis, csr, z1, N);
  k_gemm_red<<<(N + TR - 1) / TR, 256, 0, stream>>>(z1, W1, b1, dis, tcol, s, N);
  k_out   <<<1, 64, 0, stream>>>(s, W2, b2, out, 1.0f / (float)N);
}

// Round 5
// 280.043 us; speedup vs baseline: 1.5752x; 1.0718x over previous
//
#include <hip/hip_runtime.h>

#define F 128      // F_IN == H == 128
#define COUT 40
#define BSH 8      // 256 rows per bucket
#define CAP 6144   // staging slots per bucket
#define CH 8192    // edges per block in k_bucket

typedef unsigned int  u32;
typedef unsigned short u16;
typedef __attribute__((ext_vector_type(8))) short short8;
typedef __attribute__((ext_vector_type(4))) float f32x4;

__device__ inline u32 bf16_rne(float f) {
  u32 u = __float_as_uint(f);
  u += 0x7FFFu + ((u >> 16) & 1u);   // round-to-nearest-even (no NaN inputs)
  return u >> 16;
}

// ---------------- zero tcol + s + bcount ----------------
__global__ void k_zero(float* __restrict__ tcol, float* __restrict__ s,
                       int* __restrict__ bcount, int N, int nbuck) {
  int i = blockIdx.x * blockDim.x + threadIdx.x;
  if (i < N) tcol[i] = 0.f;
  if (i < nbuck) bcount[i] = 0;
  if (i < F) s[i] = 0.f;
}

// ---------------- cast X (f32) -> Xh (bf16), 8 elems/thread ----------------
__global__ void __launch_bounds__(256) k_cast(const float4* __restrict__ X,
                                              uint4* __restrict__ Xh, int nvec) {
  int i = blockIdx.x * blockDim.x + threadIdx.x;
  if (i >= nvec) return;
  float4 a = X[2 * i], b = X[2 * i + 1];
  uint4 o;
  o.x = bf16_rne(a.x) | (bf16_rne(a.y) << 16);
  o.y = bf16_rne(a.z) | (bf16_rne(a.w) << 16);
  o.z = bf16_rne(b.x) | (bf16_rne(b.y) << 16);
  o.w = bf16_rne(b.z) | (bf16_rne(b.w) << 16);
  Xh[i] = o;
}

// ---------------- cast+transpose W1 (f32 [K][H]) -> W1T (bf16 [H][K]) ----------------
__global__ void k_wt(const float* __restrict__ W1, u16* __restrict__ W1T) {
  int i = blockIdx.x * 256 + threadIdx.x;   // 64 blocks x 256 = 16384
  int k = i >> 7, n = i & 127;
  W1T[n * 128 + k] = (u16)bf16_rne(W1[i]);
}

// ---------------- phase A: bucket edges by row>>8 ----------------
__global__ void __launch_bounds__(256) k_bucket(
    const int* __restrict__ row, const int* __restrict__ col, int E,
    int* __restrict__ bcount, unsigned* __restrict__ staging, int nbuck) {
  __shared__ int hist[512];
  __shared__ int cursor[512];
  int t = threadIdx.x;
  int base = blockIdx.x * CH;
  for (int i = t; i < nbuck; i += 256) hist[i] = 0;
  __syncthreads();
  int n = E - base; if (n > CH) n = CH;
  for (int i = t; i < n; i += 256) {
    int r = row[base + i];
    atomicAdd(&hist[r >> BSH], 1);
  }
  __syncthreads();
  for (int i = t; i < nbuck; i += 256) {
    int c = hist[i];
    cursor[i] = (c > 0) ? (i * CAP + atomicAdd(&bcount[i], c)) : 0;
  }
  __syncthreads();
  for (int i = t; i < n; i += 256) {
    int r = row[base + i];
    int c = col[base + i];
    int b = r >> BSH;
    int dst = atomicAdd(&cursor[b], 1);
    if (dst < (b + 1) * CAP)
      staging[dst] = ((unsigned)(r & 255) << 17) | (unsigned)c;
  }
}

// ---------------- tiny scan over bucket counts ----------------
__global__ void k_bscan(int* __restrict__ bcount, int nbuck,
                        int* __restrict__ bbase, int* __restrict__ row_ptr,
                        int N, int E) {
  __shared__ int sm[512];
  int t = threadIdx.x;  // 512 threads
  int v = 0;
  if (t < nbuck) { v = bcount[t]; if (v > CAP) v = CAP; }
  sm[t] = v;
  __syncthreads();
  for (int off = 1; off < 512; off <<= 1) {
    int x = sm[t];
    int y = (t >= off) ? sm[t - off] : 0;
    __syncthreads();
    sm[t] = x + y;
    __syncthreads();
  }
  if (t < nbuck) bbase[t] = sm[t] - v;   // exclusive
  if (t == 0) row_ptr[N] = E;
}

// ---------------- phase B: per-bucket CSR build + row_ptr/dis + tcol ----------------
__global__ void __launch_bounds__(256) k_build(
    const unsigned* __restrict__ staging,
    const int* __restrict__ bcount, const int* __restrict__ bbase,
    int* __restrict__ row_ptr, float* __restrict__ dis,
    float* __restrict__ tcol, int* __restrict__ csr, int N) {
  __shared__ int cnt[256];
  __shared__ int cur[256];
  __shared__ float disl[256];
  int b = blockIdx.x;
  int t = threadIdx.x;
  int r0 = b << BSH;
  int nrows = N - r0; if (nrows > 256) nrows = 256;
  int ecnt = bcount[b]; if (ecnt > CAP) ecnt = CAP;
  const unsigned* sg = staging + (size_t)b * CAP;
  int gb = bbase[b];

  cnt[t] = 0;
  __syncthreads();
  for (int i = t; i < ecnt; i += 256) atomicAdd(&cnt[sg[i] >> 17], 1);
  __syncthreads();
  int d = cnt[t];
  for (int off = 1; off < 256; off <<= 1) {
    int x = cnt[t];
    int y = (t >= off) ? cnt[t - off] : 0;
    __syncthreads();
    cnt[t] = x + y;
    __syncthreads();
  }
  int excl = cnt[t] - d;
  if (t < nrows) {
    row_ptr[r0 + t] = gb + excl;
    float r = rsqrtf(1.0f + (float)d);
    dis[r0 + t] = r;
    disl[t] = r;
  }
  cur[t] = gb + excl;
  __syncthreads();
  for (int i = t; i < ecnt; i += 256) {
    unsigned p = sg[i];
    int lr = p >> 17;
    int c = (int)(p & 0x1FFFFu);
    int slot = atomicAdd(&cur[lr], 1);
    csr[slot] = c;
    atomicAdd(&tcol[c], disl[lr]);
  }
}

// ---------------- spmm: one wave per row, z1h(bf16) = Ahat * Xh ----------------
__global__ void __launch_bounds__(256) k_spmm(
    const u16* __restrict__ Xh,
    const int* __restrict__ row_ptr,
    const float* __restrict__ dis,
    const int* __restrict__ csr,
    u16* __restrict__ z1h, int N) {
  int wave = (blockIdx.x * blockDim.x + threadIdx.x) >> 6;
  int lane = threadIdx.x & 63;
  if (wave >= N) return;
  float dr = dis[wave];
  u32 sv = ((const u32*)(Xh + (size_t)wave * F))[lane];
  float2 acc = make_float2(0.f, 0.f);
  int e0 = row_ptr[wave], e1 = row_ptr[wave + 1];
  int e = e0;
  for (; e + 8 <= e1; e += 8) {
    int c[8]; u32 v[8]; float w[8];
#pragma unroll
    for (int j = 0; j < 8; ++j) c[j] = csr[e + j];
#pragma unroll
    for (int j = 0; j < 8; ++j) v[j] = ((const u32*)(Xh + (size_t)c[j] * F))[lane];
#pragma unroll
    for (int j = 0; j < 8; ++j) w[j] = dis[c[j]];
#pragma unroll
    for (int j = 0; j < 8; ++j) {
      acc.x += w[j] * __uint_as_float(v[j] << 16);
      acc.y += w[j] * __uint_as_float(v[j] & 0xFFFF0000u);
    }
  }
  for (; e + 4 <= e1; e += 4) {
    int c[4]; u32 v[4]; float w[4];
#pragma unroll
    for (int j = 0; j < 4; ++j) c[j] = csr[e + j];
#pragma unroll
    for (int j = 0; j < 4; ++j) v[j] = ((const u32*)(Xh + (size_t)c[j] * F))[lane];
#pragma unroll
    for (int j = 0; j < 4; ++j) w[j] = dis[c[j]];
#pragma unroll
    for (int j = 0; j < 4; ++j) {
      acc.x += w[j] * __uint_as_float(v[j] << 16);
      acc.y += w[j] * __uint_as_float(v[j] & 0xFFFF0000u);
    }
  }
  for (; e < e1; ++e) {
    int c = csr[e];
    float w = dis[c];
    u32 v = ((const u32*)(Xh + (size_t)c * F))[lane];
    acc.x += w * __uint_as_float(v << 16);
    acc.y += w * __uint_as_float(v & 0xFFFF0000u);
  }
  acc.x = dr * (acc.x + dr * __uint_as_float(sv << 16));
  acc.y = dr * (acc.y + dr * __uint_as_float(sv & 0xFFFF0000u));
  ((u32*)(z1h + (size_t)wave * F))[lane] = bf16_rne(acc.x) | (bf16_rne(acc.y) << 16);
}

// ---------------- MFMA GEMM (z1h@W1T + b1), relu, cw-weighted column reduce ----------------
// 64 rows/block, 4 waves; wave w owns rows 16w..16w+15, all 128 cols (8 tiles).
// A frag (16x32): lane holds z1[g0+16w + (l&15)][kb*32 + (l>>4)*8 + i]
// B frag (32x16): lane holds W1[kb*32 + (l>>4)*8 + i][16n + (l&15)] via W1T
// C frag: col = l&15, row = (l>>4)*4 + j
__global__ void __launch_bounds__(256) k_gemm_red(
    const u16* __restrict__ z1h,
    const u16* __restrict__ W1T,
    const float* __restrict__ b1,
    const float* __restrict__ dis,
    const float* __restrict__ tcol,
    float* __restrict__ s, int N) {
  __shared__ float smat[16][128];   // 8 KB
  int t = threadIdx.x;
  int w = t >> 6;
  int l = t & 63;
  int lr = l & 15;
  int lg = l >> 4;
  int g0 = blockIdx.x * 64;

  // A fragments for the whole K=128 (4 sub-tiles of 32)
  int garow = g0 + 16 * w + lr;
  if (garow >= N) garow = N - 1;              // clamped rows are masked by cw=0
  const u16* arow = z1h + (size_t)garow * F + lg * 8;
  short8 afr[4];
#pragma unroll
  for (int kb = 0; kb < 4; ++kb)
    afr[kb] = *(const short8*)(arow + kb * 32);

  // row weights for this lane's 4 C-rows
  float cw[4];
#pragma unroll
  for (int j = 0; j < 4; ++j) {
    int g = g0 + 16 * w + lg * 4 + j;
    float c = 0.f;
    if (g < N) { float d = dis[g]; c = d * (d + tcol[g]); }
    cw[j] = c;
  }

  const u16* bbase = W1T + (size_t)lr * 128 + lg * 8;
#pragma unroll
  for (int n = 0; n < 8; ++n) {
    f32x4 acc = {0.f, 0.f, 0.f, 0.f};
    const u16* bp = bbase + (size_t)(16 * n) * 128;
#pragma unroll
    for (int kb = 0; kb < 4; ++kb) {
      short8 bfr = *(const short8*)(bp + kb * 32);
      acc = __builtin_amdgcn_mfma_f32_16x16x32_bf16(afr[kb], bfr, acc, 0, 0, 0);
    }
    int colx = 16 * n + lr;
    float bb = b1[colx];
    float p = 0.f;
#pragma unroll
    for (int j = 0; j < 4; ++j) {
      float h = acc[j] + bb;
      h = h > 0.f ? h : 0.f;
      p += cw[j] * h;
    }
    smat[4 * w + lg][colx] = p;
  }
  __syncthreads();
  if (t < F) {
    float v = 0.f;
#pragma unroll
    for (int i = 0; i < 16; ++i) v += smat[i][t];
    atomicAdd(&s[t], v);
  }
}

// ---------------- finalize: out = (s/N)@W2 + b2 ----------------
__global__ void k_out(const float* __restrict__ s, const float* __restrict__ W2,
                      const float* __restrict__ b2, float* __restrict__ out,
                      float invN) {
  int j = threadIdx.x;
  if (j >= COUT) return;
  float acc = b2[j];
  for (int k = 0; k < F; ++k) acc += (s[k] * invN) * W2[k * COUT + j];
  out[j] = acc;
}

extern "C" void kernel_launch(void* const* d_in, const int* in_sizes, int n_in,
                              void* d_out, int out_size, void* d_ws, size_t ws_size,
                              hipStream_t stream) {
  const int* edge = (const int*)d_in[0];
  const float* X  = (const float*)d_in[1];
  const float* W1 = (const float*)d_in[2];
  const float* b1 = (const float*)d_in[3];
  const float* W2 = (const float*)d_in[4];
  const float* b2 = (const float*)d_in[5];
  float* out = (float*)d_out;

  int E = in_sizes[0] / 2;
  int N = in_sizes[1] / F;
  const int* row = edge;
  const int* col = edge + E;
  int nbuck = (N + 255) >> BSH;

  char* w = (char*)d_ws;
  auto alloc = [&](size_t bytes) {
    char* p = w;
    w += (bytes + 255) & ~(size_t)255;
    return p;
  };
  float*    tcol    = (float*)alloc((size_t)N * 4);
  float*    dis     = (float*)alloc((size_t)N * 4);
  int*      row_ptr = (int*)alloc(((size_t)N + 1) * 4);
  float*    s       = (float*)alloc(512);
  int*      bcount  = (int*)alloc(512 * 4);
  int*      bbase   = (int*)alloc(512 * 4);
  u16*      Xh      = (u16*)alloc((size_t)N * F * 2);
  u16*      W1T     = (u16*)alloc((size_t)F * F * 2);
  unsigned* staging = (unsigned*)alloc((size_t)nbuck * CAP * 4);
  int*      csr     = (int*)alloc((size_t)E * 4);
  u16*      z1h     = (u16*)alloc((size_t)N * F * 2);

  int nvec = (N * F) / 8;   // N*F divisible by 8

  k_zero  <<<(N + 255) / 256, 256, 0, stream>>>(tcol, s, bcount, N, nbuck);
  k_cast  <<<(nvec + 255) / 256, 256, 0, stream>>>((const float4*)X, (uint4*)Xh, nvec);
  k_wt    <<<64, 256, 0, stream>>>(W1, W1T);
  k_bucket<<<(E + CH - 1) / CH, 256, 0, stream>>>(row, col, E, bcount, staging, nbuck);
  k_bscan <<<1, 512, 0, stream>>>(bcount, nbuck, bbase, row_ptr, N, E);
  k_build <<<nbuck, 256, 0, stream>>>(staging, bcount, bbase, row_ptr, dis, tcol, csr, N);
  k_spmm  <<<(N + 3) / 4, 256, 0, stream>>>(Xh, row_ptr, dis, csr, z1h, N);
  k_gemm_red<<<(N + 63) / 64, 256, 0, stream>>>(z1h, W1T, b1, dis, tcol, s, N);
  k_out   <<<1, 64, 0, stream>>>(s, W2, b2, out, 1.0f / (float)N);
}

// Round 6
// 223.269 us; speedup vs baseline: 1.9758x; 1.2543x over previous
//
#include <hip/hip_runtime.h>

#define F 128      // F_IN == H == 128
#define COUT 40
#define BSH 8      // 256 rows/cols per bucket
#define CAP 6144   // staging slots per bucket
#define CH 8192    // edges per block in k_bucket

typedef unsigned int  u32;
typedef unsigned short u16;
typedef __attribute__((ext_vector_type(8))) short short8;
typedef __attribute__((ext_vector_type(4))) float f32x4;

__device__ inline u32 bf16_rne(float f) {
  u32 u = __float_as_uint(f);
  u += 0x7FFFu + ((u >> 16) & 1u);   // round-to-nearest-even (no NaN inputs)
  return u >> 16;
}

// ---------------- zero s + bucket counters ----------------
__global__ void k_zero(float* __restrict__ s, int* __restrict__ bcount,
                       int* __restrict__ bcount2, int nbuck) {
  int i = blockIdx.x * blockDim.x + threadIdx.x;
  if (i < nbuck) { bcount[i] = 0; bcount2[i] = 0; }
  if (i < F) s[i] = 0.f;
}

// ---------------- cast X (f32) -> Xh (bf16), 8 elems/thread ----------------
__global__ void __launch_bounds__(256) k_cast(const float4* __restrict__ X,
                                              uint4* __restrict__ Xh, int nvec) {
  int i = blockIdx.x * blockDim.x + threadIdx.x;
  if (i >= nvec) return;
  float4 a = X[2 * i], b = X[2 * i + 1];
  uint4 o;
  o.x = bf16_rne(a.x) | (bf16_rne(a.y) << 16);
  o.y = bf16_rne(a.z) | (bf16_rne(a.w) << 16);
  o.z = bf16_rne(b.x) | (bf16_rne(b.y) << 16);
  o.w = bf16_rne(b.z) | (bf16_rne(b.w) << 16);
  Xh[i] = o;
}

// ---------------- cast+transpose W1 (f32 [K][H]) -> W1T (bf16 [H][K]) ----------------
__global__ void k_wt(const float* __restrict__ W1, u16* __restrict__ W1T) {
  int i = blockIdx.x * 256 + threadIdx.x;   // 64 blocks x 256 = 16384
  int k = i >> 7, n = i & 127;
  W1T[n * 128 + k] = (u16)bf16_rne(W1[i]);
}

// ---------------- phase A: bucket edges by row>>8 AND col>>8 ----------------
__global__ void __launch_bounds__(256) k_bucket(
    const int* __restrict__ row, const int* __restrict__ col, int E,
    int* __restrict__ bcount, unsigned* __restrict__ staging,
    int* __restrict__ bcount2, unsigned* __restrict__ staging2, int nbuck) {
  __shared__ int hist[512];
  __shared__ int cursor[512];
  __shared__ int hist2[512];
  __shared__ int cursor2[512];
  int t = threadIdx.x;
  int base = blockIdx.x * CH;
  for (int i = t; i < nbuck; i += 256) { hist[i] = 0; hist2[i] = 0; }
  __syncthreads();
  int n = E - base; if (n > CH) n = CH;
  for (int i = t; i < n; i += 256) {
    int r = row[base + i], c = col[base + i];
    atomicAdd(&hist[r >> BSH], 1);
    atomicAdd(&hist2[c >> BSH], 1);
  }
  __syncthreads();
  for (int i = t; i < nbuck; i += 256) {
    int c1 = hist[i];
    cursor[i] = (c1 > 0) ? (i * CAP + atomicAdd(&bcount[i], c1)) : 0;
    int c2 = hist2[i];
    cursor2[i] = (c2 > 0) ? (i * CAP + atomicAdd(&bcount2[i], c2)) : 0;
  }
  __syncthreads();
  for (int i = t; i < n; i += 256) {
    int r = row[base + i], c = col[base + i];
    int b1 = r >> BSH;
    int d1 = atomicAdd(&cursor[b1], 1);
    if (d1 < (b1 + 1) * CAP)
      staging[d1] = ((unsigned)(r & 255) << 17) | (unsigned)c;
    int b2 = c >> BSH;
    int d2 = atomicAdd(&cursor2[b2], 1);
    if (d2 < (b2 + 1) * CAP)
      staging2[d2] = ((unsigned)(c & 255) << 17) | (unsigned)r;
  }
}

// ---------------- tiny scan over row-bucket counts ----------------
__global__ void k_bscan(int* __restrict__ bcount, int nbuck,
                        int* __restrict__ bbase, int* __restrict__ row_ptr,
                        int N, int E) {
  __shared__ int sm[512];
  int t = threadIdx.x;  // 512 threads
  int v = 0;
  if (t < nbuck) { v = bcount[t]; if (v > CAP) v = CAP; }
  sm[t] = v;
  __syncthreads();
  for (int off = 1; off < 512; off <<= 1) {
    int x = sm[t];
    int y = (t >= off) ? sm[t - off] : 0;
    __syncthreads();
    sm[t] = x + y;
    __syncthreads();
  }
  if (t < nbuck) bbase[t] = sm[t] - v;   // exclusive
  if (t == 0) row_ptr[N] = E;
}

// ---------------- phase B: per-bucket CSR build + row_ptr/dis ----------------
__global__ void __launch_bounds__(256) k_build(
    const unsigned* __restrict__ staging,
    const int* __restrict__ bcount, const int* __restrict__ bbase,
    int* __restrict__ row_ptr, float* __restrict__ dis,
    int* __restrict__ csr, int N) {
  __shared__ int cnt[256];
  __shared__ int cur[256];
  int b = blockIdx.x;
  int t = threadIdx.x;
  int r0 = b << BSH;
  int nrows = N - r0; if (nrows > 256) nrows = 256;
  int ecnt = bcount[b]; if (ecnt > CAP) ecnt = CAP;
  const unsigned* sg = staging + (size_t)b * CAP;
  int gb = bbase[b];

  cnt[t] = 0;
  __syncthreads();
  for (int i = t; i < ecnt; i += 256) atomicAdd(&cnt[sg[i] >> 17], 1);
  __syncthreads();
  int d = cnt[t];
  for (int off = 1; off < 256; off <<= 1) {
    int x = cnt[t];
    int y = (t >= off) ? cnt[t - off] : 0;
    __syncthreads();
    cnt[t] = x + y;
    __syncthreads();
  }
  int excl = cnt[t] - d;
  if (t < nrows) {
    row_ptr[r0 + t] = gb + excl;
    dis[r0 + t] = rsqrtf(1.0f + (float)d);
  }
  cur[t] = gb + excl;
  __syncthreads();
  for (int i = t; i < ecnt; i += 256) {
    unsigned p = sg[i];
    int lr = p >> 17;
    int c = (int)(p & 0x1FFFFu);
    int slot = atomicAdd(&cur[lr], 1);
    csr[slot] = c;
  }
}

// ---------------- tcol via col-buckets: tcol[c] = sum dis[row] ----------------
__global__ void __launch_bounds__(256) k_tcol(
    const unsigned* __restrict__ staging2,
    const int* __restrict__ bcount2,
    const float* __restrict__ dis,
    float* __restrict__ tcol, int N) {
  __shared__ float lacc[256];
  int b = blockIdx.x;
  int t = threadIdx.x;
  lacc[t] = 0.f;
  __syncthreads();
  int ecnt = bcount2[b]; if (ecnt > CAP) ecnt = CAP;
  const unsigned* sg = staging2 + (size_t)b * CAP;
  for (int i = t; i < ecnt; i += 256) {
    unsigned p = sg[i];
    int lc = p >> 17;
    int r = (int)(p & 0x1FFFFu);
    atomicAdd(&lacc[lc], dis[r]);
  }
  __syncthreads();
  int c = (b << BSH) + t;
  if (c < N) tcol[c] = lacc[t];
}

// ---------------- spmm: one wave per row, z1h(bf16) = Ahat * Xh ----------------
__global__ void __launch_bounds__(256) k_spmm(
    const u16* __restrict__ Xh,
    const int* __restrict__ row_ptr,
    const float* __restrict__ dis,
    const int* __restrict__ csr,
    u16* __restrict__ z1h, int N) {
  int wave = (blockIdx.x * blockDim.x + threadIdx.x) >> 6;
  int lane = threadIdx.x & 63;
  if (wave >= N) return;
  float dr = dis[wave];
  u32 sv = ((const u32*)(Xh + (size_t)wave * F))[lane];
  float2 acc = make_float2(0.f, 0.f);
  int e0 = row_ptr[wave], e1 = row_ptr[wave + 1];
  int e = e0;
  for (; e + 8 <= e1; e += 8) {
    int c[8]; u32 v[8]; float w[8];
#pragma unroll
    for (int j = 0; j < 8; ++j) c[j] = csr[e + j];
#pragma unroll
    for (int j = 0; j < 8; ++j) v[j] = ((const u32*)(Xh + (size_t)c[j] * F))[lane];
#pragma unroll
    for (int j = 0; j < 8; ++j) w[j] = dis[c[j]];
#pragma unroll
    for (int j = 0; j < 8; ++j) {
      acc.x += w[j] * __uint_as_float(v[j] << 16);
      acc.y += w[j] * __uint_as_float(v[j] & 0xFFFF0000u);
    }
  }
  for (; e + 4 <= e1; e += 4) {
    int c[4]; u32 v[4]; float w[4];
#pragma unroll
    for (int j = 0; j < 4; ++j) c[j] = csr[e + j];
#pragma unroll
    for (int j = 0; j < 4; ++j) v[j] = ((const u32*)(Xh + (size_t)c[j] * F))[lane];
#pragma unroll
    for (int j = 0; j < 4; ++j) w[j] = dis[c[j]];
#pragma unroll
    for (int j = 0; j < 4; ++j) {
      acc.x += w[j] * __uint_as_float(v[j] << 16);
      acc.y += w[j] * __uint_as_float(v[j] & 0xFFFF0000u);
    }
  }
  for (; e < e1; ++e) {
    int c = csr[e];
    float w = dis[c];
    u32 v = ((const u32*)(Xh + (size_t)c * F))[lane];
    acc.x += w * __uint_as_float(v << 16);
    acc.y += w * __uint_as_float(v & 0xFFFF0000u);
  }
  acc.x = dr * (acc.x + dr * __uint_as_float(sv << 16));
  acc.y = dr * (acc.y + dr * __uint_as_float(sv & 0xFFFF0000u));
  ((u32*)(z1h + (size_t)wave * F))[lane] = bf16_rne(acc.x) | (bf16_rne(acc.y) << 16);
}

// ---------------- MFMA GEMM (z1h@W1T + b1), relu, cw-weighted column reduce ----------------
__global__ void __launch_bounds__(256) k_gemm_red(
    const u16* __restrict__ z1h,
    const u16* __restrict__ W1T,
    const float* __restrict__ b1,
    const float* __restrict__ dis,
    const float* __restrict__ tcol,
    float* __restrict__ s, int N) {
  __shared__ float smat[16][128];   // 8 KB
  int t = threadIdx.x;
  int w = t >> 6;
  int l = t & 63;
  int lr = l & 15;
  int lg = l >> 4;
  int g0 = blockIdx.x * 64;

  int garow = g0 + 16 * w + lr;
  if (garow >= N) garow = N - 1;              // clamped rows masked by cw=0
  const u16* arow = z1h + (size_t)garow * F + lg * 8;
  short8 afr[4];
#pragma unroll
  for (int kb = 0; kb < 4; ++kb)
    afr[kb] = *(const short8*)(arow + kb * 32);

  float cw[4];
#pragma unroll
  for (int j = 0; j < 4; ++j) {
    int g = g0 + 16 * w + lg * 4 + j;
    float c = 0.f;
    if (g < N) { float d = dis[g]; c = d * (d + tcol[g]); }
    cw[j] = c;
  }

  const u16* bbase = W1T + (size_t)lr * 128 + lg * 8;
#pragma unroll
  for (int n = 0; n < 8; ++n) {
    f32x4 acc = {0.f, 0.f, 0.f, 0.f};
    const u16* bp = bbase + (size_t)(16 * n) * 128;
#pragma unroll
    for (int kb = 0; kb < 4; ++kb) {
      short8 bfr = *(const short8*)(bp + kb * 32);
      acc = __builtin_amdgcn_mfma_f32_16x16x32_bf16(afr[kb], bfr, acc, 0, 0, 0);
    }
    int colx = 16 * n + lr;
    float bb = b1[colx];
    float p = 0.f;
#pragma unroll
    for (int j = 0; j < 4; ++j) {
      float h = acc[j] + bb;
      h = h > 0.f ? h : 0.f;
      p += cw[j] * h;
    }
    smat[4 * w + lg][colx] = p;
  }
  __syncthreads();
  if (t < F) {
    float v = 0.f;
#pragma unroll
    for (int i = 0; i < 16; ++i) v += smat[i][t];
    atomicAdd(&s[t], v);
  }
}

// ---------------- finalize: out = (s/N)@W2 + b2 ----------------
__global__ void k_out(const float* __restrict__ s, const float* __restrict__ W2,
                      const float* __restrict__ b2, float* __restrict__ out,
                      float invN) {
  int j = threadIdx.x;
  if (j >= COUT) return;
  float acc = b2[j];
  for (int k = 0; k < F; ++k) acc += (s[k] * invN) * W2[k * COUT + j];
  out[j] = acc;
}

extern "C" void kernel_launch(void* const* d_in, const int* in_sizes, int n_in,
                              void* d_out, int out_size, void* d_ws, size_t ws_size,
                              hipStream_t stream) {
  const int* edge = (const int*)d_in[0];
  const float* X  = (const float*)d_in[1];
  const float* W1 = (const float*)d_in[2];
  const float* b1 = (const float*)d_in[3];
  const float* W2 = (const float*)d_in[4];
  const float* b2 = (const float*)d_in[5];
  float* out = (float*)d_out;

  int E = in_sizes[0] / 2;
  int N = in_sizes[1] / F;
  const int* row = edge;
  const int* col = edge + E;
  int nbuck = (N + 255) >> BSH;

  char* w = (char*)d_ws;
  auto alloc = [&](size_t bytes) {
    char* p = w;
    w += (bytes + 255) & ~(size_t)255;
    return p;
  };
  float*    tcol     = (float*)alloc((size_t)N * 4);
  float*    dis      = (float*)alloc((size_t)N * 4);
  int*      row_ptr  = (int*)alloc(((size_t)N + 1) * 4);
  float*    s        = (float*)alloc(512);
  int*      bcount   = (int*)alloc(512 * 4);
  int*      bbase    = (int*)alloc(512 * 4);
  int*      bcount2  = (int*)alloc(512 * 4);
  u16*      Xh       = (u16*)alloc((size_t)N * F * 2);
  u16*      W1T      = (u16*)alloc((size_t)F * F * 2);
  unsigned* staging  = (unsigned*)alloc((size_t)nbuck * CAP * 4);
  unsigned* staging2 = (unsigned*)alloc((size_t)nbuck * CAP * 4);
  int*      csr      = (int*)alloc((size_t)E * 4);
  u16*      z1h      = (u16*)alloc((size_t)N * F * 2);

  int nvec = (N * F) / 8;   // N*F divisible by 8

  k_zero  <<<(nbuck + 255) / 256, 256, 0, stream>>>(s, bcount, bcount2, nbuck);
  k_cast  <<<(nvec + 255) / 256, 256, 0, stream>>>((const float4*)X, (uint4*)Xh, nvec);
  k_wt    <<<64, 256, 0, stream>>>(W1, W1T);
  k_bucket<<<(E + CH - 1) / CH, 256, 0, stream>>>(row, col, E, bcount, staging,
                                                  bcount2, staging2, nbuck);
  k_bscan <<<1, 512, 0, stream>>>(bcount, nbuck, bbase, row_ptr, N, E);
  k_build <<<nbuck, 256, 0, stream>>>(staging, bcount, bbase, row_ptr, dis, csr, N);
  k_tcol  <<<nbuck, 256, 0, stream>>>(staging2, bcount2, dis, tcol, N);
  k_spmm  <<<(N + 3) / 4, 256, 0, stream>>>(Xh, row_ptr, dis, csr, z1h, N);
  k_gemm_red<<<(N + 63) / 64, 256, 0, stream>>>(z1h, W1T, b1, dis, tcol, s, N);
  k_out   <<<1, 64, 0, stream>>>(s, W2, b2, out, 1.0f / (float)N);
}